// Round 13
// baseline (68.949 us; speedup 1.0000x reference)
//
#include <hip/hip_runtime.h>

// Cubic B-spline prefilter (Unser), periodic, axes 2,3,4 of (2,3,160,160,160) fp32.
//
// R12 = R11 (66.3 us) with the slab doubled to 80 rows: halo read amplification
// 1.8x -> 1.4x (112 unique rows per 80 output rows), cutting slab's L2/L3 read
// traffic ~176 -> ~137 MB. Everything else verbatim-validated:
//   - scale-folding (unscaled recursions, x216 once at final NT store)
//   - no-wrap split (warm/tail bases via one select, literal-offset loops)
//   - k_d2s: LDS-staged [160x64] tile, (512,6), chunk-20 register sweeps
//   - slab: T-trick, d4 remap rr=tid>>3, XOR swizzle, XCD-coherent block map,
//     NT final store so out bypasses L3 (x + ws = 196 MB stay L3-resident)
// Register model (R7/R8 forensics): per-SIMD VGPR pool ~512 thread-equivalents;
// launch_bounds cap = 512/(min waves/EU). (640,7) -> cap 73 >> ~32 live.

#define NAX   160
#define PLN   25600      // 160*160
#define VOL   4096000    // 160*PLN
#define ZP    (-0.26794919243112270647f)   // sqrt(3)-2
#define KW    16         // truncated warm-up (z^16 ~ 7.4e-10)
#define SCALE 216.0f     // 6^3, applied once at the final store
#define SR    80         // slab rows

// ---------------- Kernel A: axis-2, LDS-staged full-axis tile ---------------
__global__ __launch_bounds__(512, 6)
void k_d2s(const float* __restrict__ in, float* __restrict__ out)
{
    __shared__ float T[NAX * 64];          // 40 KB, layout [row][64]
    const float z = ZP;
    const int t    = threadIdx.x;
    const int lane = t & 63, wv = t >> 6;  // col-in-tile, wave(=chunk) 0..7
    const int g  = blockIdx.x;             // 0..2399
    const int v  = g / 400;                // volume (b,c) 0..5
    const int i0 = (g - v * 400) * 64;     // col base in flattened (d3,d4)
    const float* src = in  + (size_t)v * VOL + i0;
    float*       dst = out + (size_t)v * VOL + i0;

    #pragma unroll
    for (int k = 0; k < 20; ++k) {
        const int r = wv + 8 * k;
        T[r * 64 + lane] = src[(size_t)r * PLN + lane];
    }
    __syncthreads();

    const int c = lane, n0 = wv * 20;
    const int wb = (n0 == 0) ? (NAX - KW) : (n0 - KW);     // warm base
    const int tb = (n0 == NAX - 20) ? 0 : (n0 + 20);       // tail base

    const float* Tw = T + wb * 64 + c;
    float st = 0.f;
    #pragma unroll
    for (int s = 0; s < KW; ++s)
        st = fmaf(z, st, Tw[s * 64]);
    const float* Tm = T + n0 * 64 + c;
    float f[20];
    #pragma unroll
    for (int s = 0; s < 20; ++s) {
        st = fmaf(z, st, Tm[s * 64]);
        f[s] = st;
    }
    const float* Tt = T + tb * 64 + c;
    float Ta = 0.f, zp = z;
    #pragma unroll
    for (int k = 0; k < KW; ++k) {
        st = fmaf(z, st, Tt[k * 64]);
        Ta = fmaf(zp, st, Ta);
        zp *= z;
    }
    float sm = -Ta;
    #pragma unroll
    for (int s = 19; s >= 0; --s) {
        sm = z * (sm - f[s]);
        dst[(size_t)(n0 + s) * PLN + c] = sm;   // unscaled -> ws
    }
}

// ---------------- Kernel B: fused axes 3+4, 80-row slab ---------------------
__device__ __forceinline__ int swz(int r, int c) {
    return r * NAX + (c ^ (r & 31));
}

__global__ __launch_bounds__(640, 7)
void slab_d3d4(const float* __restrict__ src, float* __restrict__ dst)
{
    __shared__ float Y[SR * NAX];        // 51.2 KB exchange buffer
    const float z = ZP;
    const int tid = threadIdx.x;         // 0..639

    // XCD-coherent decode (bijective over 1920): b = 16m + 8q + j
    const int b   = blockIdx.x;
    const int q   = (b >> 3) & 1;        // slab 0..1
    const int p   = ((b >> 4) << 3) + (b & 7);   // plane 0..959
    const int R0  = SR * q;
    const float* pin  = src + (size_t)p * PLN;
    float*       pout = dst + (size_t)p * PLN;

    float f[20];

    // ---- d3: thread (c, h) -> rows R0+20h .. R0+20h+19, column c -----------
    {
        const int c  = tid % NAX;
        const int h  = tid / NAX;        // 0..3
        const int n0 = R0 + 20 * h;
        const int wb = (n0 == 0) ? (NAX - KW) : (n0 - KW);
        const int tb = (n0 == NAX - 20) ? 0 : (n0 + 20);

        const float* pw = pin + wb * NAX + c;
        float st = 0.0f;
        #pragma unroll
        for (int s = 0; s < KW; ++s)     // causal warm-up
            st = fmaf(z, st, pw[s * NAX]);
        const float* pm = pin + n0 * NAX + c;
        #pragma unroll
        for (int s = 0; s < 20; ++s) {   // causal outputs
            st = fmaf(z, st, pm[s * NAX]);
            f[s] = st;
        }
        const float* pt = pin + tb * NAX + c;
        float Ta = 0.0f, zp = z;         // T-trick
        #pragma unroll
        for (int k = 0; k < KW; ++k) {
            st = fmaf(z, st, pt[k * NAX]);
            Ta = fmaf(zp, st, Ta);
            zp *= z;
        }
        float sm = -Ta;
        #pragma unroll
        for (int s = 19; s >= 0; --s) { sm = z * (sm - f[s]); f[s] = sm; }

        const int lr0 = 20 * h;          // publish slab rows (local 0..79)
        #pragma unroll
        for (int s = 0; s < 20; ++s)
            Y[swz(lr0 + s, c)] = f[s];
    }
    __syncthreads();

    // ---- d4: thread (rr, mq); remap rr=tid>>3 spreads banks ----------------
    {
        const int rr = tid >> 3;         // 0..79
        const int mq = tid & 7;          // 0..7
        const int m0 = 20 * mq;
        const int wb = (m0 == 0) ? (NAX - KW) : (m0 - KW);
        const int tb = (m0 == NAX - 20) ? 0 : (m0 + 20);
        const int xo = rr & 31;
        const float* Yr = Y + rr * NAX;

        float st = 0.0f;
        #pragma unroll
        for (int s = 0; s < KW; ++s)
            st = fmaf(z, st, Yr[(wb + s) ^ xo]);
        #pragma unroll
        for (int s = 0; s < 20; ++s) {
            st = fmaf(z, st, Yr[(m0 + s) ^ xo]);
            f[s] = st;
        }
        float Ta = 0.0f, zp = z;
        #pragma unroll
        for (int k = 0; k < KW; ++k) {
            st = fmaf(z, st, Yr[(tb + k) ^ xo]);
            Ta = fmaf(zp, st, Ta);
            zp *= z;
        }
        float sm = -Ta;
        #pragma unroll
        for (int s = 19; s >= 0; --s) { sm = z * (sm - f[s]); f[s] = sm; }

        __syncthreads();                 // ALL Y reads done before overwrite
        float* Yw = Y + rr * NAX;
        #pragma unroll
        for (int s = 0; s < 20; ++s)
            Yw[(m0 + s) ^ xo] = f[s];
    }
    __syncthreads();

    // ---- coalesced NT store, x216 ------------------------------------------
    #pragma unroll
    for (int k = 0; k < 20; ++k) {
        const int idx = tid + 640 * k;   // 0..12799 (4 full rows per instr)
        const int lr  = idx / NAX;
        const int c   = idx - lr * NAX;
        __builtin_nontemporal_store(SCALE * Y[swz(lr, c)],
                                    &pout[(R0 + lr) * NAX + c]);
    }
}

// ---------------- Fallback: in-place full-plane kernel (R3, with x216) ------
__global__ __launch_bounds__(640, 2)
void pass_d3d4(float* __restrict__ buf)
{
    __shared__ float P[PLN];
    const float z = ZP;
    const int tid = threadIdx.x;
    float* plane = buf + (size_t)blockIdx.x * PLN;

    const int c  = tid % NAX;
    const int tq = tid / NAX;
    const int n0 = tq * 40;

    #pragma unroll
    for (int k = 0; k < 40; ++k) {
        const int r = 4 * k + tq;
        P[swz(r, c)] = plane[r * NAX + c];
    }
    __syncthreads();

    float f[40];
    {
        float st = 0.0f;
        #pragma unroll
        for (int s = 0; s < KW; ++s) {
            int r = n0 - KW + s; if (r < 0) r += NAX;
            st = fmaf(z, st, P[swz(r, c)]);
        }
        #pragma unroll
        for (int s = 0; s < 40; ++s) {
            st = fmaf(z, st, P[swz(n0 + s, c)]);
            f[s] = st;
        }
        __syncthreads();
        #pragma unroll
        for (int s = 0; s < 40; ++s) P[swz(n0 + s, c)] = f[s];
        __syncthreads();
        float sm = 0.0f;
        #pragma unroll
        for (int s = KW - 1; s >= 0; --s) {
            int r = n0 + 40 + s; if (r >= NAX) r -= NAX;
            sm = z * (sm - P[swz(r, c)]);
        }
        __syncthreads();
        #pragma unroll
        for (int s = 39; s >= 0; --s) { sm = z * (sm - f[s]); P[swz(n0 + s, c)] = sm; }
        __syncthreads();
    }
    {
        const int rr = c;
        float st = 0.0f;
        #pragma unroll
        for (int s = 0; s < KW; ++s) {
            int cc = n0 - KW + s; if (cc < 0) cc += NAX;
            st = fmaf(z, st, P[swz(rr, cc)]);
        }
        #pragma unroll
        for (int s = 0; s < 40; ++s) {
            st = fmaf(z, st, P[swz(rr, n0 + s)]);
            f[s] = st;
        }
        __syncthreads();
        #pragma unroll
        for (int s = 0; s < 40; ++s) P[swz(rr, n0 + s)] = f[s];
        __syncthreads();
        float sm = 0.0f;
        #pragma unroll
        for (int s = KW - 1; s >= 0; --s) {
            int cc = n0 + 40 + s; if (cc >= NAX) cc -= NAX;
            sm = z * (sm - P[swz(rr, cc)]);
        }
        __syncthreads();
        #pragma unroll
        for (int s = 39; s >= 0; --s) { sm = z * (sm - f[s]); P[swz(rr, n0 + s)] = sm; }
        __syncthreads();
    }
    #pragma unroll
    for (int k = 0; k < 40; ++k) {
        const int r = 4 * k + tq;
        plane[r * NAX + c] = SCALE * P[swz(r, c)];
    }
}

extern "C" void kernel_launch(void* const* d_in, const int* in_sizes, int n_in,
                              void* d_out, int out_size, void* d_ws, size_t ws_size,
                              hipStream_t stream) {
    (void)in_sizes; (void)n_in; (void)out_size;
    const float* x = (const float*)d_in[0];
    float* out = (float*)d_out;
    float* ws  = (float*)d_ws;

    const size_t need = (size_t)6 * VOL * sizeof(float);   // 98.3 MB intermediate
    if (ws_size >= need) {
        k_d2s    <<<2400, 512, 0, stream>>>(x, ws);    // in -> ws (unscaled)
        slab_d3d4<<<1920, 640, 0, stream>>>(ws, out);  // ws -> out (x216 at store)
    } else {
        k_d2s    <<<2400, 512, 0, stream>>>(x, out);
        pass_d3d4<<<960,  640, 0, stream>>>(out);      // fallback (x216 at store)
    }
}

// Round 14
// 66.691 us; speedup vs baseline: 1.0339x; 1.0339x over previous
//
#include <hip/hip_runtime.h>

// Cubic B-spline prefilter (Unser), periodic, axes 2,3,4 of (2,3,160,160,160) fp32.
//
// R13 = R11 config (66.3 us; slab REVERTED to 40-row — R12's 80-row slab was
// neutral-to-negative) + float4 tile load in k_d2s (4 rows per wave-instr,
// 5 instrs instead of 20; LDS b128 write pattern exactly 8 bank-cycles =
// conflict-free).
// Validated mechanics kept verbatim:
//   - scale-folding (unscaled recursions, x216 once at final NT store)
//   - no-wrap split (warm/tail bases via one select, literal-offset loops)
//   - slab: T-trick, d4 remap rr=tid>>3, XOR swizzle, XCD-coherent block map,
//     NT final store so out bypasses L3 (x + ws = 196 MB stay L3-resident)

#define NAX   160
#define PLN   25600      // 160*160
#define VOL   4096000    // 160*PLN
#define ZP    (-0.26794919243112270647f)   // sqrt(3)-2
#define KW    16         // truncated warm-up (z^16 ~ 7.4e-10)
#define SCALE 216.0f     // 6^3, applied once at the final store

// ---------------- Kernel A: axis-2, LDS-staged full-axis tile ---------------
__global__ __launch_bounds__(512, 6)
void k_d2s(const float* __restrict__ in, float* __restrict__ out)
{
    __shared__ __align__(16) float T[NAX * 64];   // 40 KB, layout [row][64]
    const float z = ZP;
    const int t    = threadIdx.x;
    const int lane = t & 63, wv = t >> 6;  // col-in-tile, wave(=chunk) 0..7
    const int g  = blockIdx.x;             // 0..2399
    const int v  = g / 400;                // volume (b,c) 0..5
    const int i0 = (g - v * 400) * 64;     // col base in flattened (d3,d4)
    const float* src = in  + (size_t)v * VOL + i0;
    float*       dst = out + (size_t)v * VOL + i0;

    // ---- float4 tile load: 16 lanes x 16B cover one 256B row; 4 rows/instr.
    //      LDS write: word residues (4q+i) mod 32 cover each bank exactly
    //      2x per row-subgroup -> 8 bank-cycles per b128 = conflict-free.
    {
        const int qd = lane & 15;          // float4 index within row
        const int rs = lane >> 4;          // row-subgroup 0..3
        #pragma unroll
        for (int j = 0; j < 5; ++j) {
            const int r = wv + 8 * (4 * j + rs);   // rows {wv+8k}
            const float4 w = *reinterpret_cast<const float4*>(
                                 src + (size_t)r * PLN + 4 * qd);
            *reinterpret_cast<float4*>(&T[r * 64 + 4 * qd]) = w;
        }
    }
    __syncthreads();

    const int c = lane, n0 = wv * 20;
    const int wb = (n0 == 0) ? (NAX - KW) : (n0 - KW);     // warm base
    const int tb = (n0 == NAX - 20) ? 0 : (n0 + 20);       // tail base

    const float* Tw = T + wb * 64 + c;
    float st = 0.f;
    #pragma unroll
    for (int s = 0; s < KW; ++s)           // causal warm-up
        st = fmaf(z, st, Tw[s * 64]);
    const float* Tm = T + n0 * 64 + c;
    float f[20];
    #pragma unroll
    for (int s = 0; s < 20; ++s) {         // causal outputs
        st = fmaf(z, st, Tm[s * 64]);
        f[s] = st;
    }
    const float* Tt = T + tb * 64 + c;
    float Ta = 0.f, zp = z;                // T-trick: v(n0+20) = -Ta
    #pragma unroll
    for (int k = 0; k < KW; ++k) {
        st = fmaf(z, st, Tt[k * 64]);
        Ta = fmaf(zp, st, Ta);
        zp *= z;                           // constant-folds under unroll
    }
    float sm = -Ta;                        // anticausal sweep, direct store
    #pragma unroll
    for (int s = 19; s >= 0; --s) {
        sm = z * (sm - f[s]);
        dst[(size_t)(n0 + s) * PLN + c] = sm;   // unscaled -> ws
    }
}

// ---------------- Kernel B: fused axes 3+4, 40-row slab (VERBATIM R11) ------
__device__ __forceinline__ int swz(int r, int c) {
    return r * NAX + (c ^ (r & 31));
}

__global__ __launch_bounds__(320, 6)
void slab_d3d4(const float* __restrict__ src, float* __restrict__ dst)
{
    __shared__ float Y[40 * NAX];        // 25.6 KB exchange buffer
    const float z = ZP;
    const int tid = threadIdx.x;         // 0..319

    // XCD-coherent decode: all 4 slabs of plane p share blockIdx%8
    const int b   = blockIdx.x;
    const int q   = (b >> 3) & 3;        // slab 0..3
    const int p   = ((b >> 5) << 3) + (b & 7);   // plane 0..959
    const int R0  = 40 * q;
    const float* pin  = src + (size_t)p * PLN;
    float*       pout = dst + (size_t)p * PLN;

    float f[20];

    // ---- d3: thread (c, h) -> rows R0+20h .. R0+20h+19, column c -----------
    {
        const int c  = tid % NAX;
        const int h  = tid / NAX;        // 0..1
        const int n0 = R0 + 20 * h;
        const int wb = (n0 == 0) ? (NAX - KW) : (n0 - KW);
        const int tb = (n0 == NAX - 20) ? 0 : (n0 + 20);

        const float* pw = pin + wb * NAX + c;
        float st = 0.0f;
        #pragma unroll
        for (int s = 0; s < KW; ++s)     // causal warm-up
            st = fmaf(z, st, pw[s * NAX]);
        const float* pm = pin + n0 * NAX + c;
        #pragma unroll
        for (int s = 0; s < 20; ++s) {   // causal outputs
            st = fmaf(z, st, pm[s * NAX]);
            f[s] = st;
        }
        const float* pt = pin + tb * NAX + c;
        float Ta = 0.0f, zp = z;         // T-trick
        #pragma unroll
        for (int k = 0; k < KW; ++k) {
            st = fmaf(z, st, pt[k * NAX]);
            Ta = fmaf(zp, st, Ta);
            zp *= z;
        }
        float sm = -Ta;
        #pragma unroll
        for (int s = 19; s >= 0; --s) { sm = z * (sm - f[s]); f[s] = sm; }

        const int lr0 = 20 * h;          // publish slab rows (local 0..39)
        #pragma unroll
        for (int s = 0; s < 20; ++s)
            Y[swz(lr0 + s, c)] = f[s];
    }
    __syncthreads();

    // ---- d4: thread (rr, mq); remap rr=tid>>3 spreads banks ----------------
    {
        const int rr = tid >> 3;         // 0..39
        const int mq = tid & 7;          // 0..7
        const int m0 = 20 * mq;
        const int wb = (m0 == 0) ? (NAX - KW) : (m0 - KW);
        const int tb = (m0 == NAX - 20) ? 0 : (m0 + 20);
        const int xo = rr & 31;
        const float* Yr = Y + rr * NAX;

        float st = 0.0f;
        #pragma unroll
        for (int s = 0; s < KW; ++s)
            st = fmaf(z, st, Yr[(wb + s) ^ xo]);
        #pragma unroll
        for (int s = 0; s < 20; ++s) {
            st = fmaf(z, st, Yr[(m0 + s) ^ xo]);
            f[s] = st;
        }
        float Ta = 0.0f, zp = z;
        #pragma unroll
        for (int k = 0; k < KW; ++k) {
            st = fmaf(z, st, Yr[(tb + k) ^ xo]);
            Ta = fmaf(zp, st, Ta);
            zp *= z;
        }
        float sm = -Ta;
        #pragma unroll
        for (int s = 19; s >= 0; --s) { sm = z * (sm - f[s]); f[s] = sm; }

        __syncthreads();                 // ALL Y reads done before overwrite
        float* Yw = Y + rr * NAX;
        #pragma unroll
        for (int s = 0; s < 20; ++s)
            Yw[(m0 + s) ^ xo] = f[s];
    }
    __syncthreads();

    // ---- coalesced NT store, x216 ------------------------------------------
    #pragma unroll
    for (int k = 0; k < 20; ++k) {
        const int idx = tid + 320 * k;
        const int lr  = idx / NAX;
        const int c   = idx - lr * NAX;
        __builtin_nontemporal_store(SCALE * Y[swz(lr, c)],
                                    &pout[(R0 + lr) * NAX + c]);
    }
}

// ---------------- Fallback: in-place full-plane kernel (R3, with x216) ------
__global__ __launch_bounds__(640, 2)
void pass_d3d4(float* __restrict__ buf)
{
    __shared__ float P[PLN];
    const float z = ZP;
    const int tid = threadIdx.x;
    float* plane = buf + (size_t)blockIdx.x * PLN;

    const int c  = tid % NAX;
    const int tq = tid / NAX;
    const int n0 = tq * 40;

    #pragma unroll
    for (int k = 0; k < 40; ++k) {
        const int r = 4 * k + tq;
        P[swz(r, c)] = plane[r * NAX + c];
    }
    __syncthreads();

    float f[40];
    {
        float st = 0.0f;
        #pragma unroll
        for (int s = 0; s < KW; ++s) {
            int r = n0 - KW + s; if (r < 0) r += NAX;
            st = fmaf(z, st, P[swz(r, c)]);
        }
        #pragma unroll
        for (int s = 0; s < 40; ++s) {
            st = fmaf(z, st, P[swz(n0 + s, c)]);
            f[s] = st;
        }
        __syncthreads();
        #pragma unroll
        for (int s = 0; s < 40; ++s) P[swz(n0 + s, c)] = f[s];
        __syncthreads();
        float sm = 0.0f;
        #pragma unroll
        for (int s = KW - 1; s >= 0; --s) {
            int r = n0 + 40 + s; if (r >= NAX) r -= NAX;
            sm = z * (sm - P[swz(r, c)]);
        }
        __syncthreads();
        #pragma unroll
        for (int s = 39; s >= 0; --s) { sm = z * (sm - f[s]); P[swz(n0 + s, c)] = sm; }
        __syncthreads();
    }
    {
        const int rr = c;
        float st = 0.0f;
        #pragma unroll
        for (int s = 0; s < KW; ++s) {
            int cc = n0 - KW + s; if (cc < 0) cc += NAX;
            st = fmaf(z, st, P[swz(rr, cc)]);
        }
        #pragma unroll
        for (int s = 0; s < 40; ++s) {
            st = fmaf(z, st, P[swz(rr, n0 + s)]);
            f[s] = st;
        }
        __syncthreads();
        #pragma unroll
        for (int s = 0; s < 40; ++s) P[swz(rr, n0 + s)] = f[s];
        __syncthreads();
        float sm = 0.0f;
        #pragma unroll
        for (int s = KW - 1; s >= 0; --s) {
            int cc = n0 + 40 + s; if (cc >= NAX) cc -= NAX;
            sm = z * (sm - P[swz(rr, cc)]);
        }
        __syncthreads();
        #pragma unroll
        for (int s = 39; s >= 0; --s) { sm = z * (sm - f[s]); P[swz(rr, n0 + s)] = sm; }
        __syncthreads();
    }
    #pragma unroll
    for (int k = 0; k < 40; ++k) {
        const int r = 4 * k + tq;
        plane[r * NAX + c] = SCALE * P[swz(r, c)];
    }
}

extern "C" void kernel_launch(void* const* d_in, const int* in_sizes, int n_in,
                              void* d_out, int out_size, void* d_ws, size_t ws_size,
                              hipStream_t stream) {
    (void)in_sizes; (void)n_in; (void)out_size;
    const float* x = (const float*)d_in[0];
    float* out = (float*)d_out;
    float* ws  = (float*)d_ws;

    const size_t need = (size_t)6 * VOL * sizeof(float);   // 98.3 MB intermediate
    if (ws_size >= need) {
        k_d2s    <<<2400, 512, 0, stream>>>(x, ws);    // in -> ws (unscaled)
        slab_d3d4<<<3840, 320, 0, stream>>>(ws, out);  // ws -> out (x216 at store)
    } else {
        k_d2s    <<<2400, 512, 0, stream>>>(x, out);
        pass_d3d4<<<960,  640, 0, stream>>>(out);      // fallback (x216 at store)
    }
}